// Round 1
// baseline (191.604 us; speedup 1.0000x reference)
//
#include <hip/hip_runtime.h>

// NetVLAD fused: s = x·W, a = softmax_k(s), v = a^T x + (sum a)·C
// x: [64,784,512] f32, W/C: [512,32] f32, out: [64, 512*32] f32
#define NB 64
#define HW 784
#define DD 512
#define KK 32
#define BLOCKS_PER_B 14
#define PIX_PER_BLOCK 56   // 784/14
#define CHUNK 8
#define NCHUNK 7           // 56/8

__global__ __launch_bounds__(256) void netvlad_fused(
    const float* __restrict__ x, const float* __restrict__ W,
    const float* __restrict__ C, float* __restrict__ out)
{
    __shared__ float4 x4[CHUNK * 128];        // 8 pixels * 512 f32 = 16 KB
    __shared__ float  spart[CHUNK][KK][9];    // partial dots, +1 pad (9 KB)
    __shared__ float  abuf[CHUNK][KK];        // softmax result / asum reduce (1 KB)

    const int tid = threadIdx.x;
    const int k   = tid & 31;   // cluster
    const int gd  = tid >> 5;   // d-group 0..7
    const int bid = blockIdx.x;
    const int b   = bid / BLOCKS_PER_B;
    const int pb  = (bid % BLOCKS_PER_B) * PIX_PER_BLOCK;

    const float* xb = x + (size_t)b * HW * DD;

    // Register-cache this thread's W column slice: d = (gd + 8*i)*4 + c, k fixed
    float4 Wc[16];
#pragma unroll
    for (int i = 0; i < 16; ++i) {
        const int dbase = (gd + 8 * i) * 4;
        Wc[i].x = W[(dbase + 0) * KK + k];
        Wc[i].y = W[(dbase + 1) * KK + k];
        Wc[i].z = W[(dbase + 2) * KK + k];
        Wc[i].w = W[(dbase + 3) * KK + k];
    }

    float4 acc[16];
#pragma unroll
    for (int i = 0; i < 16; ++i) acc[i] = make_float4(0.f, 0.f, 0.f, 0.f);
    float asum_part = 0.f;   // this thread's (pixel-slot gd, cluster k) sum of a

    for (int c0 = 0; c0 < NCHUNK; ++c0) {
        const int pixbase = pb + c0 * CHUNK;

        // ---- phase 0: stage 8 pixels of x into LDS (contiguous copy) ----
        const float4* src = (const float4*)(xb + (size_t)pixbase * DD);
#pragma unroll
        for (int j = 0; j < 4; ++j)
            x4[tid + j * 256] = src[tid + j * 256];
        __syncthreads();

        // ---- phase A: partial s[p][k] over this thread's 64 d values ----
        for (int p = 0; p < CHUNK; ++p) {
            float part = 0.f;
#pragma unroll
            for (int i = 0; i < 16; ++i) {
                const float4 xv = x4[p * 128 + gd + 8 * i];
                part += xv.x * Wc[i].x + xv.y * Wc[i].y
                      + xv.z * Wc[i].z + xv.w * Wc[i].w;
            }
            spart[p][k][gd] = part;
        }
        __syncthreads();

        // ---- phase B: softmax over k (thread = pixel-slot gd, cluster k) ----
        {
            float s = 0.f;
#pragma unroll
            for (int g = 0; g < 8; ++g) s += spart[gd][k][g];
            float m = s;
#pragma unroll
            for (int msk = 16; msk >= 1; msk >>= 1)
                m = fmaxf(m, __shfl_xor(m, msk));
            const float e = __expf(s - m);
            float sum = e;
#pragma unroll
            for (int msk = 16; msk >= 1; msk >>= 1)
                sum += __shfl_xor(sum, msk);
            const float a = e / sum;
            abuf[gd][k] = a;
            asum_part += a;
        }
        __syncthreads();

        // ---- phase C: acc[d][k] += a[p][k] * x[p][d] ----
        for (int p = 0; p < CHUNK; ++p) {
            const float a = abuf[p][k];
#pragma unroll
            for (int i = 0; i < 16; ++i) {
                const float4 xv = x4[p * 128 + gd + 8 * i];
                acc[i].x += xv.x * a;
                acc[i].y += xv.y * a;
                acc[i].z += xv.z * a;
                acc[i].w += xv.w * a;
            }
        }
        __syncthreads();
    }

    // ---- epilogue: reduce block-local asum[k] across the 8 pixel slots ----
    abuf[gd][k] = asum_part;
    __syncthreads();
    float asum = 0.f;
#pragma unroll
    for (int p = 0; p < 8; ++p) asum += abuf[p][k];

    // ---- C correction + atomic merge into global output ----
    float* ob = out + (size_t)b * (DD * KK);
#pragma unroll
    for (int i = 0; i < 16; ++i) {
        const int dbase = (gd + 8 * i) * 4;
        const float v0 = acc[i].x + asum * C[(dbase + 0) * KK + k];
        const float v1 = acc[i].y + asum * C[(dbase + 1) * KK + k];
        const float v2 = acc[i].z + asum * C[(dbase + 2) * KK + k];
        const float v3 = acc[i].w + asum * C[(dbase + 3) * KK + k];
        atomicAdd(&ob[(dbase + 0) * KK + k], v0);
        atomicAdd(&ob[(dbase + 1) * KK + k], v1);
        atomicAdd(&ob[(dbase + 2) * KK + k], v2);
        atomicAdd(&ob[(dbase + 3) * KK + k], v3);
    }
}

extern "C" void kernel_launch(void* const* d_in, const int* in_sizes, int n_in,
                              void* d_out, int out_size, void* d_ws, size_t ws_size,
                              hipStream_t stream) {
    const float* x = (const float*)d_in[0];
    const float* W = (const float*)d_in[1];
    const float* C = (const float*)d_in[2];
    float* out = (float*)d_out;

    // Output is accumulated with atomics -> must start at zero every call.
    hipMemsetAsync(out, 0, (size_t)out_size * sizeof(float), stream);

    netvlad_fused<<<dim3(NB * BLOCKS_PER_B), dim3(256), 0, stream>>>(x, W, C, out);
}